// Round 3
// baseline (225.574 us; speedup 1.0000x reference)
//
#include <hip/hip_runtime.h>

// MultiHeadAttention: N=4, S=T=2048, E=512, H=8, HD=64. fp32 in/out, bf16 MFMA compute.
// R3: attn on 32x32x16 MFMA with O^T orientation (no alpha shuffles), conflict-free XOR
// swizzles, Q pre-scaled to exp2 domain, V-transpose fused into QKV GEMM. 4 dispatches.

#define DEV __device__ __forceinline__

typedef unsigned short u16;
typedef unsigned int u32;
typedef __bf16 bf16x8 __attribute__((ext_vector_type(8)));
typedef float f32x4 __attribute__((ext_vector_type(4)));
typedef float f32x16 __attribute__((ext_vector_type(16)));

#define MFMA16(A, B, C) __builtin_amdgcn_mfma_f32_16x16x32_bf16(A, B, C, 0, 0, 0)
#define MFMA32(A, B, C) __builtin_amdgcn_mfma_f32_32x32x16_bf16(A, B, C, 0, 0, 0)

#define SC 0.18033688f  // (1/8) * log2(e): Q pre-scale -> scores in exp2 domain

DEV u16 f2bf(float f) {  // RNE
  u32 u = __builtin_bit_cast(u32, f);
  u += 0x7fffu + ((u >> 16) & 1u);
  return (u16)(u >> 16);
}
DEV u16 f2bf_ru(float f) {  // round-half-up, for non-negative P values
  u32 u = __builtin_bit_cast(u32, f);
  return (u16)((u + 0x8000u) >> 16);
}

// async global->LDS, 16B/lane; LDS dst must be wave-uniform base + lane*16.
DEV void cp16(void* l, const void* g) {
  __builtin_amdgcn_global_load_lds(
      (const __attribute__((address_space(1))) u32*)g,
      (__attribute__((address_space(3))) u32*)l, 16, 0, 0);
}

// ---------------- fused cast: q,k,v (4096 blocks each) + 4 weights (256 each) ----------------
__global__ __launch_bounds__(256) void cast_all(
    const float* __restrict__ q, const float* __restrict__ k, const float* __restrict__ v,
    const float* __restrict__ wq, const float* __restrict__ wk, const float* __restrict__ wv,
    const float* __restrict__ wp,
    u16* qo, u16* ko, u16* vo, u16* wqo, u16* wko, u16* wvo, u16* wpo) {
  int b = blockIdx.x, tid = threadIdx.x;
  const float* s;
  u16* d;
  int off;
  float sc = 1.f;
  if (b < 12288) {
    int which = b >> 12;
    s = (which == 0) ? q : (which == 1) ? k : v;
    d = (which == 0) ? qo : (which == 1) ? ko : vo;
    off = (b & 4095) * 256;
  } else {
    int wb = b - 12288, which = wb >> 8;
    s = (which == 0) ? wq : (which == 1) ? wk : (which == 2) ? wv : wp;
    d = (which == 0) ? wqo : (which == 1) ? wko : (which == 2) ? wvo : wpo;
    off = (wb & 255) * 256;
    if (which == 0) sc = SC;  // Wq pre-scaled: scores land in exp2 domain
  }
  int i = off + tid;
  float4 f = ((const float4*)s)[i];
  ushort4 o;
  o.x = f2bf(f.x * sc); o.y = f2bf(f.y * sc); o.z = f2bf(f.z * sc); o.w = f2bf(f.w * sc);
  ((ushort4*)d)[i] = o;
}

// ---------------- GEMM core: C[m,n] = sum_k A[m,k]*W[n,k] (m97 structure) ----------------
DEV void gemm_loop(const u16* __restrict__ A, const u16* __restrict__ W,
                   u16* As, u16* Bs, int m0, int n0, int tid, f32x4 acc[4][4]) {
  const int lane = tid & 63, wid = tid >> 6;
  const int wm = wid & 1, wn = wid >> 1;
  const int l15 = lane & 15, l4 = lane >> 4;
  for (int kt = 0; kt < 512; kt += 32) {
    __syncthreads();
#pragma unroll
    for (int i = 0; i < 2; ++i) {
      int c = tid + 256 * i;
      int row = c >> 2, kc = (c & 3) * 8;
      cp16(&As[c * 8], A + (m0 + row) * 512 + kt + kc);
      cp16(&Bs[c * 8], W + (n0 + row) * 512 + kt + kc);
    }
    __syncthreads();
    bf16x8 af[4], bfr[4];
#pragma unroll
    for (int f = 0; f < 4; ++f) {
      af[f]  = *(const bf16x8*)&As[(wm * 64 + f * 16 + l15) * 32 + l4 * 8];
      bfr[f] = *(const bf16x8*)&Bs[(wn * 64 + f * 16 + l15) * 32 + l4 * 8];
    }
#pragma unroll
    for (int fm = 0; fm < 4; ++fm)
#pragma unroll
      for (int fn = 0; fn < 4; ++fn)
        acc[fm][fn] = MFMA16(af[fm], bfr[fn], acc[fm][fn]);
  }
}

// Fused QKV projection. grid (12,64): blockIdx.x>>2 selects Q/K/V.
// Q: bias scaled by SC (W pre-scaled at cast). V: written TRANSPOSED to vt[nh*64+d][2048 t].
__global__ __launch_bounds__(256) void gemm_qkv(
    const u16* __restrict__ qx, const u16* __restrict__ kx, const u16* __restrict__ vx,
    const u16* __restrict__ wq, const u16* __restrict__ wk, const u16* __restrict__ wv,
    const float* __restrict__ bq, const float* __restrict__ bk, const float* __restrict__ bv,
    u16* qp, u16* kp, u16* vt) {
  __shared__ u16 As[128 * 32];
  __shared__ u16 Bs[128 * 32];
  const int wsel = blockIdx.x >> 2;
  const u16* A = (wsel == 0) ? qx : (wsel == 1) ? kx : vx;
  const u16* W = (wsel == 0) ? wq : (wsel == 1) ? wk : wv;
  const float* bias = (wsel == 0) ? bq : (wsel == 1) ? bk : bv;
  const int n0 = (blockIdx.x & 3) * 128, m0 = blockIdx.y * 128;
  const int tid = threadIdx.x, lane = tid & 63, wid = tid >> 6;
  const int wm = wid & 1, wn = wid >> 1;
  const int l15 = lane & 15, l4 = lane >> 4;

  f32x4 acc[4][4] = {};
  gemm_loop(A, W, As, Bs, m0, n0, tid, acc);

  if (wsel < 2) {
    u16* C = (wsel == 0) ? qp : kp;
    const float bscale = (wsel == 0) ? SC : 1.f;
#pragma unroll
    for (int fn = 0; fn < 4; ++fn) {
      int col = n0 + wn * 64 + fn * 16 + l15;
      float bvv = bias[col] * bscale;
#pragma unroll
      for (int fm = 0; fm < 4; ++fm) {
        int rowb = m0 + wm * 64 + fm * 16 + l4 * 4;
#pragma unroll
        for (int r = 0; r < 4; ++r)
          C[(rowb + r) * 512 + col] = f2bf(acc[fm][fn][r] + bvv);
      }
    }
  } else {  // V: transposed store, b64 per (fm,fn): 4 consecutive t
    const int nIdx = m0 >> 11, tb = m0 & 2047;
#pragma unroll
    for (int fn = 0; fn < 4; ++fn) {
      int col = n0 + wn * 64 + fn * 16 + l15;
      int vtrow = (nIdx * 8 + (col >> 6)) * 64 + (col & 63);
      float bvv = bias[col];
#pragma unroll
      for (int fm = 0; fm < 4; ++fm) {
        int t = tb + wm * 64 + fm * 16 + l4 * 4;
        ushort4 o;
        o.x = f2bf(acc[fm][fn][0] + bvv);
        o.y = f2bf(acc[fm][fn][1] + bvv);
        o.z = f2bf(acc[fm][fn][2] + bvv);
        o.w = f2bf(acc[fm][fn][3] + bvv);
        *(ushort4*)(vt + vtrow * 2048 + t) = o;
      }
    }
  }
}

// Final projection: fp32 out.
__global__ __launch_bounds__(256) void gemm_out(const u16* __restrict__ A,
                                                const u16* __restrict__ W,
                                                const float* __restrict__ bias,
                                                float* __restrict__ C) {
  __shared__ u16 As[128 * 32];
  __shared__ u16 Bs[128 * 32];
  const int n0 = blockIdx.x * 128, m0 = blockIdx.y * 128;
  const int tid = threadIdx.x, lane = tid & 63, wid = tid >> 6;
  const int wm = wid & 1, wn = wid >> 1;
  const int l15 = lane & 15, l4 = lane >> 4;

  f32x4 acc[4][4] = {};
  gemm_loop(A, W, As, Bs, m0, n0, tid, acc);

#pragma unroll
  for (int fn = 0; fn < 4; ++fn) {
    int col = n0 + wn * 64 + fn * 16 + l15;
    float bvv = bias[col];
#pragma unroll
    for (int fm = 0; fm < 4; ++fm) {
      int rowb = m0 + wm * 64 + fm * 16 + l4 * 4;
#pragma unroll
      for (int r = 0; r < 4; ++r)
        C[(rowb + r) * 512 + col] = acc[fm][fn][r] + bvv;
    }
  }
}

// ---------------- Flash attention, causal, 32x32x16 MFMA ----------------
// Block: 4 waves, Q tile 128 rows (wave w owns m-strip w*32..+32), K/V tile 128.
// S^T = K*Q^T (C/D cols = m), O^T = V^T*P^T (C/D cols = m) -> softmax state stays
// in the owning lane, zero shuffles for alpha/l. P round-trips LDS in-wave only.
// Swizzles: 16B-chunk XOR for cp16-staged K/V/Q (conflict-free b128 reads),
// 8B-chunk XOR (c8 ^ (m&31)) for P (conflict-free b64 write+read).
__global__ __launch_bounds__(256) void attn_kernel(const u16* __restrict__ Qg,
                                                   const u16* __restrict__ Kg,
                                                   const u16* __restrict__ Vt,
                                                   u16* __restrict__ Yg) {
  __shared__ u16 Ps[128 * 128];  // P^T as [m][t]; bytes [0,16K) double as Q staging
  __shared__ u16 Ks[128 * 64];   // [t][d], 8 chunks/row, phys = c ^ (t&7)
  __shared__ u16 Vs[64 * 128];   // [d][t], 16 chunks/row, phys = c ^ (d&15)

  const int bid = blockIdx.x;
  const int nh = bid & 31;
  const int p = bid >> 5;
  const int qt = (p < 8) ? (15 - p) : (p - 8);  // complementary pairs sum to 17 steps
  const int n = nh >> 3, h = nh & 7;
  const int tid = threadIdx.x, lane = tid & 63, w = tid >> 6;
  const int l31 = lane & 31, lh = lane >> 5;
  const int s0 = qt * 128;

  const u16* Qb = Qg + (n * 2048 + s0) * 512 + h * 64;
  const u16* Kb = Kg + n * 2048 * 512 + h * 64;
  const u16* Vb = Vt + nh * 64 * 2048;

  // stage Q tile (128x64) into Ps[0..16KB)
#pragma unroll
  for (int i = 0; i < 4; ++i) {
    int ci = tid + 256 * i;
    int m = ci >> 3, pc = ci & 7;
    cp16(&Ps[ci * 8], Qb + m * 512 + ((pc ^ (m & 7)) * 8));
  }
  __syncthreads();
  const int qm = w * 32 + l31;  // own m (local row / S^T column)
  bf16x8 qf[4];                 // Q B-frags, loop-invariant
#pragma unroll
  for (int ks = 0; ks < 4; ++ks)
    qf[ks] = *(const bf16x8*)&Ps[qm * 64 + (((2 * ks + lh) ^ (qm & 7)) * 8)];

  f32x16 accO[2] = {};
  float mrow = -1e30f, lrow = 0.f;

  for (int it = 0; it <= qt; ++it) {
    const int t0 = it * 128;
    __syncthreads();  // prior step's K/V reads complete
#pragma unroll
    for (int i = 0; i < 4; ++i) {  // K tile: 1024 chunks
      int ci = tid + 256 * i;
      int t = ci >> 3, pc = ci & 7;
      cp16(&Ks[ci * 8], Kb + (t0 + t) * 512 + ((pc ^ (t & 7)) * 8));
    }
#pragma unroll
    for (int i = 0; i < 4; ++i) {  // V^T tile: 1024 chunks
      int ci = tid + 256 * i;
      int d = ci >> 4, pc = ci & 15;
      cp16(&Vs[ci * 8], Vb + d * 2048 + t0 + ((pc ^ (d & 15)) * 8));
    }
    __syncthreads();

    const bool diag = (it == qt);
    const int nf = diag ? (w + 1) : 4;  // frags f>w fully masked on diag step: skip

    // ---- S^T = K Q^T: frag f covers t in [f*32, f*32+32) ----
    f32x16 st[4];
#pragma unroll
    for (int f = 0; f < 4; ++f)
      if (f < nf) {
        f32x16 a = {};
        int tr = f * 32 + l31;
#pragma unroll
        for (int ks = 0; ks < 4; ++ks) {
          bf16x8 kf = *(const bf16x8*)&Ks[tr * 64 + (((2 * ks + lh) ^ (tr & 7)) * 8)];
          a = MFMA32(kf, qf[ks], a);
        }
        if (diag && f == w) {  // partial mask on the diagonal frag
#pragma unroll
          for (int r = 0; r < 16; ++r) {
            int trow = f * 32 + (r & 3) + 8 * (r >> 2) + 4 * lh;
            a[r] = (trow > qm) ? -1e30f : a[r];
          }
        }
        st[f] = a;
      }

    // ---- online softmax (exp2 domain; scores pre-scaled). Lane pair (l31, l31+32)
    //      co-owns column m; one shfl_xor(32) completes each reduction. ----
    float rmax = -1e30f;
#pragma unroll
    for (int f = 0; f < 4; ++f)
      if (f < nf)
#pragma unroll
        for (int r = 0; r < 16; ++r) rmax = fmaxf(rmax, st[f][r]);
    rmax = fmaxf(rmax, __shfl_xor(rmax, 32));
    float mnew = fmaxf(mrow, rmax);
    float alpha = __builtin_amdgcn_exp2f(mrow - mnew);
    mrow = mnew;
    float rsum = 0.f;
#pragma unroll
    for (int f = 0; f < 4; ++f)
      if (f < nf)
#pragma unroll
        for (int r = 0; r < 16; ++r) {
          float pv = __builtin_amdgcn_exp2f(st[f][r] - mnew);
          st[f][r] = pv;
          rsum += pv;
        }
    rsum += __shfl_xor(rsum, 32);
    lrow = lrow * alpha + rsum;
    accO[0] = accO[0] * alpha;  // accO cols = own m: no shuffle needed
    accO[1] = accO[1] * alpha;

    // ---- P -> LDS, own column m only (in-wave visibility; barriers elsewhere) ----
    const int pbase = qm * 128;
#pragma unroll
    for (int f = 0; f < 4; ++f)
      if (f < nf)
#pragma unroll
        for (int g = 0; g < 4; ++g) {
          ushort4 pk;
          pk.x = f2bf_ru(st[f][4 * g + 0]);
          pk.y = f2bf_ru(st[f][4 * g + 1]);
          pk.z = f2bf_ru(st[f][4 * g + 2]);
          pk.w = f2bf_ru(st[f][4 * g + 3]);
          int c8 = f * 8 + 2 * g + lh;  // t = f*32+8g+4lh+[0..3] -> 8B chunk
          *(ushort4*)&Ps[pbase + ((c8 ^ (qm & 31)) * 4)] = pk;
        }

    // ---- O^T += V^T P^T ----
    const int nks = nf * 2;
#pragma unroll
    for (int ks = 0; ks < 8; ++ks)
      if (ks < nks) {
        int c8a = 4 * ks + 2 * lh;  // t = ks*16+lh*8+[0..7] -> two 8B chunks
        uint2 lo = *(const uint2*)&Ps[pbase + ((c8a ^ (qm & 31)) * 4)];
        uint2 hi = *(const uint2*)&Ps[pbase + (((c8a + 1) ^ (qm & 31)) * 4)];
        uint4 pb4;
        pb4.x = lo.x; pb4.y = lo.y; pb4.z = hi.x; pb4.w = hi.y;
        bf16x8 pb = __builtin_bit_cast(bf16x8, pb4);
#pragma unroll
        for (int fd = 0; fd < 2; ++fd) {
          int d = fd * 32 + l31;
          bf16x8 vf = *(const bf16x8*)&Vs[d * 128 + (((2 * ks + lh) ^ (d & 15)) * 8)];
          accO[fd] = MFMA32(vf, pb, accO[fd]);
        }
      }
  }

  // ---- epilogue: O^T[d][m] -> Y[s=s0+qm][h*64+d], b64 stores (4 consecutive d) ----
  float inv = 1.0f / lrow;
  u16* Yb = Yg + (n * 2048 + s0 + qm) * 512 + h * 64;
#pragma unroll
  for (int fd = 0; fd < 2; ++fd)
#pragma unroll
    for (int g = 0; g < 4; ++g) {
      ushort4 o;
      o.x = f2bf(accO[fd][4 * g + 0] * inv);
      o.y = f2bf(accO[fd][4 * g + 1] * inv);
      o.z = f2bf(accO[fd][4 * g + 2] * inv);
      o.w = f2bf(accO[fd][4 * g + 3] * inv);
      *(ushort4*)(Yb + fd * 32 + 8 * g + 4 * lh) = o;
    }
}

extern "C" void kernel_launch(void* const* d_in, const int* in_sizes, int n_in,
                              void* d_out, int out_size, void* d_ws, size_t ws_size,
                              hipStream_t stream) {
  (void)in_sizes; (void)n_in; (void)out_size; (void)ws_size;
  const float* query = (const float*)d_in[0];
  const float* key_  = (const float*)d_in[1];
  const float* value = (const float*)d_in[2];
  // d_in[3] = attn_mask (tril) — causal, applied structurally
  const float* Wq = (const float*)d_in[4];
  const float* bq = (const float*)d_in[5];
  const float* Wk = (const float*)d_in[6];
  const float* bk = (const float*)d_in[7];
  const float* Wv = (const float*)d_in[8];
  const float* bv = (const float*)d_in[9];
  const float* Wp = (const float*)d_in[10];
  const float* bp = (const float*)d_in[11];

  char* ws = (char*)d_ws;  // ~52 MB
  u16* qx  = (u16*)(ws);                // 8 MB; reused as y after q-proj consumed
  u16* kx  = (u16*)(ws + 8388608);      // 8 MB
  u16* vx  = (u16*)(ws + 16777216);     // 8 MB
  u16* wqx = (u16*)(ws + 25165824);     // 512 KB each
  u16* wkx = (u16*)(ws + 25690112);
  u16* wvx = (u16*)(ws + 26214400);
  u16* wpx = (u16*)(ws + 26738688);
  u16* qp  = (u16*)(ws + 27262976);     // 8 MB
  u16* kp  = (u16*)(ws + 35651584);     // 8 MB
  u16* vt  = (u16*)(ws + 44040192);     // 8 MB, V transposed [nh*64+d][2048]
  u16* y   = qx;

  cast_all<<<13312, 256, 0, stream>>>(query, key_, value, Wq, Wk, Wv, Wp,
                                      qx, kx, vx, wqx, wkx, wvx, wpx);
  gemm_qkv<<<dim3(12, 64), 256, 0, stream>>>(qx, kx, vx, wqx, wkx, wvx,
                                             bq, bk, bv, qp, kp, vt);
  attn_kernel<<<512, 256, 0, stream>>>(qp, kp, vt, y);
  gemm_out<<<dim3(4, 64), 256, 0, stream>>>(y, wpx, bp, (float*)d_out);
}

// Round 4
// 221.930 us; speedup vs baseline: 1.0164x; 1.0164x over previous
//
#include <hip/hip_runtime.h>

// MultiHeadAttention: N=4, S=T=2048, E=512, H=8, HD=64. fp32 in/out, bf16 MFMA compute.
// R4: attn with shuffle-based P^T->B-frag conversion (no P LDS roundtrip, 32KB LDS,
// 3 blocks/CU), V-proj GEMM emitted transposed with coalesced stores. 4 dispatches.

#define DEV __device__ __forceinline__

typedef unsigned short u16;
typedef unsigned int u32;
typedef __bf16 bf16x8 __attribute__((ext_vector_type(8)));
typedef float f32x4 __attribute__((ext_vector_type(4)));
typedef float f32x16 __attribute__((ext_vector_type(16)));

#define MFMA16(A, B, C) __builtin_amdgcn_mfma_f32_16x16x32_bf16(A, B, C, 0, 0, 0)
#define MFMA32(A, B, C) __builtin_amdgcn_mfma_f32_32x32x16_bf16(A, B, C, 0, 0, 0)

#define SC 0.18033688f  // (1/8) * log2(e): Q pre-scale -> scores in exp2 domain

DEV u16 f2bf(float f) {  // RNE
  u32 u = __builtin_bit_cast(u32, f);
  u += 0x7fffu + ((u >> 16) & 1u);
  return (u16)(u >> 16);
}
// pack two non-negative floats to bf16 pair (round-half-up): 3 VALU ops
DEV u32 pk2(float lo, float hi) {
  u32 a = __builtin_bit_cast(u32, lo) + 0x8000u;
  u32 b = __builtin_bit_cast(u32, hi) + 0x8000u;
  return __builtin_amdgcn_perm(b, a, 0x07060302u);  // [b.hi16 : a.hi16]
}

// async global->LDS, 16B/lane; LDS dst must be wave-uniform base + lane*16.
DEV void cp16(void* l, const void* g) {
  __builtin_amdgcn_global_load_lds(
      (const __attribute__((address_space(1))) u32*)g,
      (__attribute__((address_space(3))) u32*)l, 16, 0, 0);
}

// ---------------- fused cast: q,k,v (4096 blocks each) + 4 weights (256 each) ----------------
__global__ __launch_bounds__(256) void cast_all(
    const float* __restrict__ q, const float* __restrict__ k, const float* __restrict__ v,
    const float* __restrict__ wq, const float* __restrict__ wk, const float* __restrict__ wv,
    const float* __restrict__ wp,
    u16* qo, u16* ko, u16* vo, u16* wqo, u16* wko, u16* wvo, u16* wpo) {
  int b = blockIdx.x, tid = threadIdx.x;
  const float* s;
  u16* d;
  int off;
  float sc = 1.f;
  if (b < 12288) {
    int which = b >> 12;
    s = (which == 0) ? q : (which == 1) ? k : v;
    d = (which == 0) ? qo : (which == 1) ? ko : vo;
    off = (b & 4095) * 256;
  } else {
    int wb = b - 12288, which = wb >> 8;
    s = (which == 0) ? wq : (which == 1) ? wk : (which == 2) ? wv : wp;
    d = (which == 0) ? wqo : (which == 1) ? wko : (which == 2) ? wvo : wpo;
    off = (wb & 255) * 256;
    if (which == 0) sc = SC;  // Wq pre-scaled: scores land in exp2 domain
  }
  int i = off + tid;
  float4 f = ((const float4*)s)[i];
  ushort4 o;
  o.x = f2bf(f.x * sc); o.y = f2bf(f.y * sc); o.z = f2bf(f.z * sc); o.w = f2bf(f.w * sc);
  ((ushort4*)d)[i] = o;
}

// ---------------- GEMM core: C[m,n] = sum_k A[m,k]*W[n,k] (m97 structure) ----------------
DEV void gemm_loop(const u16* __restrict__ A, const u16* __restrict__ W,
                   u16* As, u16* Bs, int m0, int n0, int tid, f32x4 acc[4][4]) {
  const int lane = tid & 63, wid = tid >> 6;
  const int wm = wid & 1, wn = wid >> 1;
  const int l15 = lane & 15, l4 = lane >> 4;
  for (int kt = 0; kt < 512; kt += 32) {
    __syncthreads();
#pragma unroll
    for (int i = 0; i < 2; ++i) {
      int c = tid + 256 * i;
      int row = c >> 2, kc = (c & 3) * 8;
      cp16(&As[c * 8], A + (m0 + row) * 512 + kt + kc);
      cp16(&Bs[c * 8], W + (n0 + row) * 512 + kt + kc);
    }
    __syncthreads();
    bf16x8 af[4], bfr[4];
#pragma unroll
    for (int f = 0; f < 4; ++f) {
      af[f]  = *(const bf16x8*)&As[(wm * 64 + f * 16 + l15) * 32 + l4 * 8];
      bfr[f] = *(const bf16x8*)&Bs[(wn * 64 + f * 16 + l15) * 32 + l4 * 8];
    }
#pragma unroll
    for (int fm = 0; fm < 4; ++fm)
#pragma unroll
      for (int fn = 0; fn < 4; ++fn)
        acc[fm][fn] = MFMA16(af[fm], bfr[fn], acc[fm][fn]);
  }
}

// Fused QKV projection. grid (12,64): blockIdx.x>>2 selects Q/K/V.
// Q: bias scaled by SC (W pre-scaled at cast). V computed TRANSPOSED:
// C[d'][t] = sum_k Wv[d',k]*vx[t,k] -> coalesced stores into vt[nh*64+d][2048].
__global__ __launch_bounds__(256) void gemm_qkv(
    const u16* __restrict__ qx, const u16* __restrict__ kx, const u16* __restrict__ vx,
    const u16* __restrict__ wq, const u16* __restrict__ wk, const u16* __restrict__ wv,
    const float* __restrict__ bq, const float* __restrict__ bk, const float* __restrict__ bv,
    u16* qp, u16* kp, u16* vt) {
  __shared__ u16 As[128 * 32];
  __shared__ u16 Bs[128 * 32];
  const int wsel = blockIdx.x >> 2;
  const int xq = blockIdx.x & 3;
  const u16* A = (wsel == 0) ? qx : (wsel == 1) ? kx : wv;   // wsel==2: A = Wv (role swap)
  const u16* W = (wsel == 0) ? wq : (wsel == 1) ? wk : vx;
  const float* bias = (wsel == 0) ? bq : (wsel == 1) ? bk : bv;
  const int m0 = (wsel == 2) ? xq * 128 : blockIdx.y * 128;
  const int n0 = (wsel == 2) ? blockIdx.y * 128 : xq * 128;
  const int tid = threadIdx.x, lane = tid & 63, wid = tid >> 6;
  const int wm = wid & 1, wn = wid >> 1;
  const int l15 = lane & 15, l4 = lane >> 4;

  f32x4 acc[4][4] = {};
  gemm_loop(A, W, As, Bs, m0, n0, tid, acc);

  if (wsel < 2) {
    u16* C = (wsel == 0) ? qp : kp;
    const float bscale = (wsel == 0) ? SC : 1.f;
#pragma unroll
    for (int fn = 0; fn < 4; ++fn) {
      int col = n0 + wn * 64 + fn * 16 + l15;
      float bvv = bias[col] * bscale;
#pragma unroll
      for (int fm = 0; fm < 4; ++fm) {
        int rowb = m0 + wm * 64 + fm * 16 + l4 * 4;
#pragma unroll
        for (int r = 0; r < 4; ++r)
          C[(rowb + r) * 512 + col] = f2bf(acc[fm][fn][r] + bvv);
      }
    }
  } else {  // V transposed: rows = d' (bias per row), cols = t (coalesced over l15)
    const int nIdx = n0 >> 11;
    const int tb = n0 & 2047;
#pragma unroll
    for (int fm = 0; fm < 4; ++fm) {
      int rowb = m0 + wm * 64 + fm * 16 + l4 * 4;
#pragma unroll
      for (int r = 0; r < 4; ++r) {
        int row = rowb + r;  // d' in [0,512)
        float bvv = bias[row];
        int vtrow = (nIdx * 8 + (row >> 6)) * 64 + (row & 63);
#pragma unroll
        for (int fn = 0; fn < 4; ++fn) {
          int tcol = tb + wn * 64 + fn * 16 + l15;
          vt[vtrow * 2048 + tcol] = f2bf(acc[fm][fn][r] + bvv);
        }
      }
    }
  }
}

// Final projection: fp32 out.
__global__ __launch_bounds__(256) void gemm_out(const u16* __restrict__ A,
                                                const u16* __restrict__ W,
                                                const float* __restrict__ bias,
                                                float* __restrict__ C) {
  __shared__ u16 As[128 * 32];
  __shared__ u16 Bs[128 * 32];
  const int n0 = blockIdx.x * 128, m0 = blockIdx.y * 128;
  const int tid = threadIdx.x, lane = tid & 63, wid = tid >> 6;
  const int wm = wid & 1, wn = wid >> 1;
  const int l15 = lane & 15, l4 = lane >> 4;

  f32x4 acc[4][4] = {};
  gemm_loop(A, W, As, Bs, m0, n0, tid, acc);

#pragma unroll
  for (int fn = 0; fn < 4; ++fn) {
    int col = n0 + wn * 64 + fn * 16 + l15;
    float bvv = bias[col];
#pragma unroll
    for (int fm = 0; fm < 4; ++fm) {
      int rowb = m0 + wm * 64 + fm * 16 + l4 * 4;
#pragma unroll
      for (int r = 0; r < 4; ++r)
        C[(rowb + r) * 512 + col] = acc[fm][fn][r] + bvv;
    }
  }
}

// ---------------- Flash attention, causal, 32x32x16 MFMA, no P LDS roundtrip ----------------
// Block: 4 waves, Q tile 128 rows (wave w owns m-strip [32w,32w+32)), K/V tile 128.
// S^T = K*Q^T (C/D cols = m), O^T = V^T*P^T. P^T B-frags built in-register: the C/D
// chunk layout differs from the B-frag layout only by a 4-elem chunk swap between
// lane pairs (l, l^32) -> one shfl_xor(32) per 8 t-values. LDS = K(16K)+V(16K) = 32KB.
__global__ __launch_bounds__(256) void attn_kernel(const u16* __restrict__ Qg,
                                                   const u16* __restrict__ Kg,
                                                   const u16* __restrict__ Vt,
                                                   u16* __restrict__ Yg) {
  __shared__ u16 Ks[128 * 64];  // [t][d], 8 chunks/row, phys chunk = c ^ (t&7); Q staged here first
  __shared__ u16 Vs[64 * 128];  // [d][t], 16 chunks/row, phys chunk = c ^ (d&15)

  const int bid = blockIdx.x;
  const int nh = bid & 31;
  const int p = bid >> 5;
  const int qt = (p < 8) ? (15 - p) : (p - 8);  // heavy tiles dispatched first
  const int n = nh >> 3, h = nh & 7;
  const int tid = threadIdx.x, lane = tid & 63, w = tid >> 6;
  const int l31 = lane & 31, lh = lane >> 5;
  const int s0 = qt * 128;

  const u16* Qb = Qg + (n * 2048 + s0) * 512 + h * 64;
  const u16* Kb = Kg + n * 2048 * 512 + h * 64;
  const u16* Vb = Vt + nh * 64 * 2048;

  // stage Q tile (128x64) into Ks, extract loop-invariant B-frags
#pragma unroll
  for (int i = 0; i < 4; ++i) {
    int ci = tid + 256 * i;
    int m = ci >> 3, pc = ci & 7;
    cp16(&Ks[ci * 8], Qb + m * 512 + ((pc ^ (m & 7)) * 8));
  }
  __syncthreads();
  const int qm = w * 32 + l31;  // own m (S^T column)
  bf16x8 qf[4];
#pragma unroll
  for (int ks = 0; ks < 4; ++ks)
    qf[ks] = *(const bf16x8*)&Ks[qm * 64 + (((2 * ks + lh) ^ (qm & 7)) * 8)];

  f32x16 accO[2] = {};
  float mrow = -1e30f, lrow = 0.f;

  for (int it = 0; it <= qt; ++it) {
    const int t0 = it * 128;
    __syncthreads();  // prior step's K/V reads (and initial qf reads) complete
#pragma unroll
    for (int i = 0; i < 4; ++i) {  // K tile
      int ci = tid + 256 * i;
      int t = ci >> 3, pc = ci & 7;
      cp16(&Ks[ci * 8], Kb + (t0 + t) * 512 + ((pc ^ (t & 7)) * 8));
    }
#pragma unroll
    for (int i = 0; i < 4; ++i) {  // V^T tile
      int ci = tid + 256 * i;
      int d = ci >> 4, pc = ci & 15;
      cp16(&Vs[ci * 8], Vb + d * 2048 + t0 + ((pc ^ (d & 15)) * 8));
    }
    __syncthreads();

    const bool diag = (it == qt);
    const int nf = diag ? (w + 1) : 4;  // frags beyond the diagonal are fully masked: skip

    // ---- S^T = K Q^T: frag f covers t in [32f, 32f+32) ----
    f32x16 st[4];
#pragma unroll
    for (int f = 0; f < 4; ++f)
      if (f < nf) {
        f32x16 a = {};
        int tr = f * 32 + l31;
#pragma unroll
        for (int ks = 0; ks < 4; ++ks) {
          bf16x8 kf = *(const bf16x8*)&Ks[tr * 64 + (((2 * ks + lh) ^ (tr & 7)) * 8)];
          a = MFMA32(kf, qf[ks], a);
        }
        if (diag && f == w) {
#pragma unroll
          for (int r = 0; r < 16; ++r) {
            int trow = f * 32 + (r & 3) + 8 * (r >> 2) + 4 * lh;
            a[r] = (trow > qm) ? -1e30f : a[r];
          }
        }
        st[f] = a;
      }

    // ---- online softmax (exp2 domain). Lane pair (l31, l31+32) co-owns column m. ----
    float rmax = -1e30f;
#pragma unroll
    for (int f = 0; f < 4; ++f)
      if (f < nf)
#pragma unroll
        for (int r = 0; r < 16; ++r) rmax = fmaxf(rmax, st[f][r]);
    rmax = fmaxf(rmax, __shfl_xor(rmax, 32));
    float mnew = fmaxf(mrow, rmax);
    float alpha = __builtin_amdgcn_exp2f(mrow - mnew);
    mrow = mnew;
    accO[0] = accO[0] * alpha;
    accO[1] = accO[1] * alpha;

    float rsum = 0.f;
    u32 pd[4][8];  // packed P: chunk(f,g) = dwords pd[f][2g..2g+1], t = 32f+8g+4lh+[0,4)
#pragma unroll
    for (int f = 0; f < 4; ++f)
      if (f < nf) {
#pragma unroll
        for (int r = 0; r < 16; ++r) {
          float pv = __builtin_amdgcn_exp2f(st[f][r] - mnew);
          st[f][r] = pv;
          rsum += pv;
        }
#pragma unroll
        for (int g = 0; g < 4; ++g) {
          pd[f][2 * g]     = pk2(st[f][4 * g + 0], st[f][4 * g + 1]);
          pd[f][2 * g + 1] = pk2(st[f][4 * g + 2], st[f][4 * g + 3]);
        }
      }
    rsum += __shfl_xor(rsum, 32);
    lrow = lrow * alpha + rsum;

    // ---- O^T += V^T P^T; B-frag(f,h) = [t: 32f+16h+8lh .. +8) via lane-pair chunk swap ----
#pragma unroll
    for (int f = 0; f < 4; ++f)
      if (f < nf) {
#pragma unroll
        for (int hh = 0; hh < 2; ++hh) {
          // send partner the chunk it needs: lh=0 sends odd chunk, lh=1 sends even chunk
          u32 s0 = lh ? pd[f][4 * hh + 0] : pd[f][4 * hh + 2];
          u32 s1 = lh ? pd[f][4 * hh + 1] : pd[f][4 * hh + 3];
          u32 r0 = __shfl_xor(s0, 32);
          u32 r1 = __shfl_xor(s1, 32);
          uint4 b4;
          b4.x = lh ? r0 : pd[f][4 * hh + 0];
          b4.y = lh ? r1 : pd[f][4 * hh + 1];
          b4.z = lh ? pd[f][4 * hh + 2] : r0;
          b4.w = lh ? pd[f][4 * hh + 3] : r1;
          bf16x8 pb = __builtin_bit_cast(bf16x8, b4);
          const int ks = 2 * f + hh;
#pragma unroll
          for (int fd = 0; fd < 2; ++fd) {
            int d = fd * 32 + l31;
            bf16x8 vf = *(const bf16x8*)&Vs[d * 128 + (((2 * ks + lh) ^ (d & 15)) * 8)];
            accO[fd] = MFMA32(vf, pb, accO[fd]);
          }
        }
      }
  }

  // ---- epilogue: O^T[d][m] -> Y[s=s0+qm][h*64+d], b64 stores ----
  float inv = 1.0f / lrow;
  u16* Yb = Yg + (n * 2048 + s0 + qm) * 512 + h * 64;
#pragma unroll
  for (int fd = 0; fd < 2; ++fd)
#pragma unroll
    for (int g = 0; g < 4; ++g) {
      ushort4 o;
      o.x = f2bf(accO[fd][4 * g + 0] * inv);
      o.y = f2bf(accO[fd][4 * g + 1] * inv);
      o.z = f2bf(accO[fd][4 * g + 2] * inv);
      o.w = f2bf(accO[fd][4 * g + 3] * inv);
      *(ushort4*)(Yb + fd * 32 + 8 * g + 4 * lh) = o;
    }
}

extern "C" void kernel_launch(void* const* d_in, const int* in_sizes, int n_in,
                              void* d_out, int out_size, void* d_ws, size_t ws_size,
                              hipStream_t stream) {
  (void)in_sizes; (void)n_in; (void)out_size; (void)ws_size;
  const float* query = (const float*)d_in[0];
  const float* key_  = (const float*)d_in[1];
  const float* value = (const float*)d_in[2];
  // d_in[3] = attn_mask (tril) — causal, applied structurally
  const float* Wq = (const float*)d_in[4];
  const float* bq = (const float*)d_in[5];
  const float* Wk = (const float*)d_in[6];
  const float* bk = (const float*)d_in[7];
  const float* Wv = (const float*)d_in[8];
  const float* bv = (const float*)d_in[9];
  const float* Wp = (const float*)d_in[10];
  const float* bp = (const float*)d_in[11];

  char* ws = (char*)d_ws;  // ~52 MB
  u16* qx  = (u16*)(ws);                // 8 MB; reused as y after q-proj consumed
  u16* kx  = (u16*)(ws + 8388608);      // 8 MB
  u16* vx  = (u16*)(ws + 16777216);     // 8 MB
  u16* wqx = (u16*)(ws + 25165824);     // 512 KB each
  u16* wkx = (u16*)(ws + 25690112);
  u16* wvx = (u16*)(ws + 26214400);
  u16* wpx = (u16*)(ws + 26738688);
  u16* qp  = (u16*)(ws + 27262976);     // 8 MB
  u16* kp  = (u16*)(ws + 35651584);     // 8 MB
  u16* vt  = (u16*)(ws + 44040192);     // 8 MB, V transposed [nh*64+d][2048]
  u16* y   = qx;

  cast_all<<<13312, 256, 0, stream>>>(query, key_, value, Wq, Wk, Wv, Wp,
                                      qx, kx, vx, wqx, wkx, wvx, wpx);
  gemm_qkv<<<dim3(12, 64), 256, 0, stream>>>(qx, kx, vx, wqx, wkx, wvx,
                                             bq, bk, bv, qp, kp, vt);
  attn_kernel<<<512, 256, 0, stream>>>(qp, kp, vt, y);
  gemm_out<<<dim3(4, 64), 256, 0, stream>>>(y, wpx, bp, (float*)d_out);
}

// Round 5
// 214.762 us; speedup vs baseline: 1.0503x; 1.0334x over previous
//
#include <hip/hip_runtime.h>

// MultiHeadAttention: N=4, S=T=2048, E=512, H=8, HD=64. fp32 in/out, bf16 MFMA compute.
// R5: co-residency fix. attn = 64-row Q tiles, 2-wave blocks, grid 1024 (4/CU).
// GEMMs = 128x64 tiles, 2-wave blocks (qkv 1536, out 512 blocks). 4 dispatches.

#define DEV __device__ __forceinline__

typedef unsigned short u16;
typedef unsigned int u32;
typedef __bf16 bf16x8 __attribute__((ext_vector_type(8)));
typedef float f32x4 __attribute__((ext_vector_type(4)));
typedef float f32x16 __attribute__((ext_vector_type(16)));

#define MFMA16(A, B, C) __builtin_amdgcn_mfma_f32_16x16x32_bf16(A, B, C, 0, 0, 0)
#define MFMA32(A, B, C) __builtin_amdgcn_mfma_f32_32x32x16_bf16(A, B, C, 0, 0, 0)

#define SC 0.18033688f  // (1/8) * log2(e): Q pre-scale -> scores in exp2 domain

DEV u16 f2bf(float f) {  // RNE
  u32 u = __builtin_bit_cast(u32, f);
  u += 0x7fffu + ((u >> 16) & 1u);
  return (u16)(u >> 16);
}
// pack two non-negative floats to bf16 pair (round-half-up)
DEV u32 pk2(float lo, float hi) {
  u32 a = __builtin_bit_cast(u32, lo) + 0x8000u;
  u32 b = __builtin_bit_cast(u32, hi) + 0x8000u;
  return __builtin_amdgcn_perm(b, a, 0x07060302u);  // [b.hi16 : a.hi16]
}

// async global->LDS, 16B/lane; LDS dst must be wave-uniform base + lane*16.
DEV void cp16(void* l, const void* g) {
  __builtin_amdgcn_global_load_lds(
      (const __attribute__((address_space(1))) u32*)g,
      (__attribute__((address_space(3))) u32*)l, 16, 0, 0);
}

// ---------------- fused cast ----------------
__global__ __launch_bounds__(256) void cast_all(
    const float* __restrict__ q, const float* __restrict__ k, const float* __restrict__ v,
    const float* __restrict__ wq, const float* __restrict__ wk, const float* __restrict__ wv,
    const float* __restrict__ wp,
    u16* qo, u16* ko, u16* vo, u16* wqo, u16* wko, u16* wvo, u16* wpo) {
  int b = blockIdx.x, tid = threadIdx.x;
  const float* s;
  u16* d;
  int off;
  float sc = 1.f;
  if (b < 12288) {
    int which = b >> 12;
    s = (which == 0) ? q : (which == 1) ? k : v;
    d = (which == 0) ? qo : (which == 1) ? ko : vo;
    off = (b & 4095) * 256;
  } else {
    int wb = b - 12288, which = wb >> 8;
    s = (which == 0) ? wq : (which == 1) ? wk : (which == 2) ? wv : wp;
    d = (which == 0) ? wqo : (which == 1) ? wko : (which == 2) ? wvo : wpo;
    off = (wb & 255) * 256;
    if (which == 0) sc = SC;  // Wq pre-scaled
  }
  int i = off + tid;
  float4 f = ((const float4*)s)[i];
  ushort4 o;
  o.x = f2bf(f.x * sc); o.y = f2bf(f.y * sc); o.z = f2bf(f.z * sc); o.w = f2bf(f.w * sc);
  ((ushort4*)d)[i] = o;
}

// ---------------- GEMM core: 128x64 tile (M rows of A, 64 rows of W), 2 waves ----------------
// Wave w owns m-half [64w, 64w+64) x all 64 n. acc[4][4] of 16x16.
DEV void gemm_loop_12864(const u16* __restrict__ A, const u16* __restrict__ W,
                         u16* As, u16* Bs, int m0, int n0, int tid, f32x4 acc[4][4]) {
  const int lane = tid & 63, w = tid >> 6;
  const int l15 = lane & 15, l4 = lane >> 4;
  for (int kt = 0; kt < 512; kt += 32) {
    __syncthreads();
#pragma unroll
    for (int i = 0; i < 4; ++i) {  // A tile: 512 chunks
      int c = tid + 128 * i;
      cp16(&As[c * 8], A + (m0 + (c >> 2)) * 512 + kt + (c & 3) * 8);
    }
#pragma unroll
    for (int i = 0; i < 2; ++i) {  // B tile: 256 chunks
      int c = tid + 128 * i;
      cp16(&Bs[c * 8], W + (n0 + (c >> 2)) * 512 + kt + (c & 3) * 8);
    }
    __syncthreads();
    bf16x8 af[4], bfr[4];
#pragma unroll
    for (int f = 0; f < 4; ++f) {
      af[f]  = *(const bf16x8*)&As[(w * 64 + f * 16 + l15) * 32 + l4 * 8];
      bfr[f] = *(const bf16x8*)&Bs[(f * 16 + l15) * 32 + l4 * 8];
    }
#pragma unroll
    for (int fm = 0; fm < 4; ++fm)
#pragma unroll
      for (int fn = 0; fn < 4; ++fn)
        acc[fm][fn] = MFMA16(af[fm], bfr[fn], acc[fm][fn]);
  }
}

// Fused QKV projection. Flat grid 1536: wsel = bid/512.
// wsel<2 (Q,K): m0 = (r>>3)*128 (seq), n0 = (r&7)*64 (out-dim).
// wsel==2 (V, computed transposed: C[d'][t] = Wv dot vx): m0 = (r&3)*128 (d'), n0 = (r>>2)*64 (t).
__global__ __launch_bounds__(128) void gemm_qkv(
    const u16* __restrict__ qx, const u16* __restrict__ kx, const u16* __restrict__ vx,
    const u16* __restrict__ wq, const u16* __restrict__ wk, const u16* __restrict__ wv,
    const float* __restrict__ bq, const float* __restrict__ bk, const float* __restrict__ bv,
    u16* qp, u16* kp, u16* vt) {
  __shared__ u16 As[128 * 32];
  __shared__ u16 Bs[64 * 32];
  const int bid = blockIdx.x;
  const int wsel = bid >> 9, r = bid & 511;
  const u16* A = (wsel == 0) ? qx : (wsel == 1) ? kx : wv;
  const u16* W = (wsel == 0) ? wq : (wsel == 1) ? wk : vx;
  const float* bias = (wsel == 0) ? bq : (wsel == 1) ? bk : bv;
  const int m0 = (wsel == 2) ? (r & 3) * 128 : (r >> 3) * 128;
  const int n0 = (wsel == 2) ? (r >> 2) * 64 : (r & 7) * 64;
  const int tid = threadIdx.x, lane = tid & 63, w = tid >> 6;
  const int l15 = lane & 15, l4 = lane >> 4;

  f32x4 acc[4][4] = {};
  gemm_loop_12864(A, W, As, Bs, m0, n0, tid, acc);

  if (wsel < 2) {
    u16* C = (wsel == 0) ? qp : kp;
    const float bscale = (wsel == 0) ? SC : 1.f;
#pragma unroll
    for (int fn = 0; fn < 4; ++fn) {
      int col = n0 + fn * 16 + l15;
      float bvv = bias[col] * bscale;
#pragma unroll
      for (int fm = 0; fm < 4; ++fm) {
        int rowb = m0 + w * 64 + fm * 16 + l4 * 4;
#pragma unroll
        for (int rr = 0; rr < 4; ++rr)
          C[(rowb + rr) * 512 + col] = f2bf(acc[fm][fn][rr] + bvv);
      }
    }
  } else {  // V transposed: rows = d' (bias per row), cols = t
    const int nIdx = n0 >> 11, tb = n0 & 2047;
#pragma unroll
    for (int fm = 0; fm < 4; ++fm) {
      int rowb = m0 + w * 64 + fm * 16 + l4 * 4;
#pragma unroll
      for (int rr = 0; rr < 4; ++rr) {
        int row = rowb + rr;  // d'
        float bvv = bias[row];
        int vtrow = (nIdx * 8 + (row >> 6)) * 64 + (row & 63);
#pragma unroll
        for (int fn = 0; fn < 4; ++fn)
          vt[vtrow * 2048 + tb + fn * 16 + l15] = f2bf(acc[fm][fn][rr] + bvv);
      }
    }
  }
}

// Final projection: fp32 out. Flat grid 512: m0 = (bid>>3)*128, n0 = (bid&7)*64.
__global__ __launch_bounds__(128) void gemm_out(const u16* __restrict__ A,
                                                const u16* __restrict__ W,
                                                const float* __restrict__ bias,
                                                float* __restrict__ C) {
  __shared__ u16 As[128 * 32];
  __shared__ u16 Bs[64 * 32];
  const int bid = blockIdx.x;
  const int m0 = (bid >> 3) * 128, n0 = (bid & 7) * 64;
  const int tid = threadIdx.x, lane = tid & 63, w = tid >> 6;
  const int l15 = lane & 15, l4 = lane >> 4;

  f32x4 acc[4][4] = {};
  gemm_loop_12864(A, W, As, Bs, m0, n0, tid, acc);

#pragma unroll
  for (int fn = 0; fn < 4; ++fn) {
    int col = n0 + fn * 16 + l15;
    float bvv = bias[col];
#pragma unroll
    for (int fm = 0; fm < 4; ++fm) {
      int rowb = m0 + w * 64 + fm * 16 + l4 * 4;
#pragma unroll
      for (int rr = 0; rr < 4; ++rr)
        C[(rowb + rr) * 512 + col] = acc[fm][fn][rr] + bvv;
    }
  }
}

// ---------------- Flash attention, causal, 32x32x16 MFMA, 64-row Q tiles ----------------
// Grid 1024 = 32 q-tiles x 32 nh; 2 waves/block, wave w owns m-strip [32w,32w+32).
// S^T = K*Q^T (C/D cols = m), O^T = V^T*P^T with in-register P B-frag conversion
// (lane-pair chunk swap via shfl_xor 32). LDS: K 16KB + V 16KB = 32KB.
__global__ __launch_bounds__(128) void attn_kernel(const u16* __restrict__ Qg,
                                                   const u16* __restrict__ Kg,
                                                   const u16* __restrict__ Vt,
                                                   u16* __restrict__ Yg) {
  __shared__ u16 Ks[128 * 64];  // [t][d], phys chunk = c ^ (t&7); Q (64x64) staged here first
  __shared__ u16 Vs[64 * 128];  // [d][t], phys chunk = c ^ (d&15)

  const int bid = blockIdx.x;
  const int nh = bid & 31;
  const int qt = 31 - (bid >> 5);  // heavy q-tiles first
  const int n = nh >> 3, h = nh & 7;
  const int tid = threadIdx.x, lane = tid & 63, w = tid >> 6;
  const int l31 = lane & 31, lh = lane >> 5;
  const int s0 = qt * 64;

  const u16* Qb = Qg + (n * 2048 + s0) * 512 + h * 64;
  const u16* Kb = Kg + n * 2048 * 512 + h * 64;
  const u16* Vb = Vt + nh * 64 * 2048;

  // stage Q tile (64x64) into Ks, extract loop-invariant B-frags
#pragma unroll
  for (int i = 0; i < 4; ++i) {
    int ci = tid + 128 * i;
    int m = ci >> 3, pc = ci & 7;
    cp16(&Ks[ci * 8], Qb + m * 512 + ((pc ^ (m & 7)) * 8));
  }
  __syncthreads();
  const int qm = w * 32 + l31;  // own m (S^T column), local [0,64)
  bf16x8 qf[4];
#pragma unroll
  for (int ks = 0; ks < 4; ++ks)
    qf[ks] = *(const bf16x8*)&Ks[qm * 64 + (((2 * ks + lh) ^ (qm & 7)) * 8)];

  f32x16 accO[2] = {};
  float mrow = -1e30f, lrow = 0.f;

  const int ntiles = (qt >> 1) + 1;
  for (int it = 0; it < ntiles; ++it) {
    const int t0 = it * 128;
    __syncthreads();  // prior step's K/V reads (and initial qf reads) complete
#pragma unroll
    for (int i = 0; i < 8; ++i) {  // K tile: 1024 chunks
      int ci = tid + 128 * i;
      int t = ci >> 3, pc = ci & 7;
      cp16(&Ks[ci * 8], Kb + (t0 + t) * 512 + ((pc ^ (t & 7)) * 8));
    }
#pragma unroll
    for (int i = 0; i < 8; ++i) {  // V^T tile: 1024 chunks
      int ci = tid + 128 * i;
      int d = ci >> 4, pc = ci & 15;
      cp16(&Vs[ci * 8], Vb + d * 2048 + t0 + ((pc ^ (d & 15)) * 8));
    }
    __syncthreads();

    const bool diag = (it == ntiles - 1);
    // frag f (t in [t0+32f, t0+32f+32)) contributes iff t0+32f <= s0+32w+31
    const int nf = diag ? min(4, ((s0 + 32 * w + 31 - t0) >> 5) + 1) : 4;

    // ---- S^T = K Q^T ----
    f32x16 st[4];
#pragma unroll
    for (int f = 0; f < 4; ++f)
      if (f < nf) {
        f32x16 a = {};
        int tr = f * 32 + l31;
#pragma unroll
        for (int ks = 0; ks < 4; ++ks) {
          bf16x8 kf = *(const bf16x8*)&Ks[tr * 64 + (((2 * ks + lh) ^ (tr & 7)) * 8)];
          a = MFMA32(kf, qf[ks], a);
        }
        if (diag) {  // elementwise causal mask
#pragma unroll
          for (int rr = 0; rr < 16; ++rr) {
            int trow = t0 + f * 32 + (rr & 3) + 8 * (rr >> 2) + 4 * lh;
            a[rr] = (trow > s0 + qm) ? -1e30f : a[rr];
          }
        }
        st[f] = a;
      }

    // ---- online softmax (exp2 domain); lane pair (l31, l31+32) co-owns column m ----
    float rmax = -1e30f;
#pragma unroll
    for (int f = 0; f < 4; ++f)
      if (f < nf)
#pragma unroll
        for (int rr = 0; rr < 16; ++rr) rmax = fmaxf(rmax, st[f][rr]);
    rmax = fmaxf(rmax, __shfl_xor(rmax, 32));
    float mnew = fmaxf(mrow, rmax);
    float alpha = __builtin_amdgcn_exp2f(mrow - mnew);
    mrow = mnew;
    accO[0] = accO[0] * alpha;
    accO[1] = accO[1] * alpha;

    float rsum = 0.f;
    u32 pd[4][8];  // packed P: chunk(f,g) = pd[f][2g..2g+1], t = 32f+8g+4lh+[0,4)
#pragma unroll
    for (int f = 0; f < 4; ++f)
      if (f < nf) {
#pragma unroll
        for (int rr = 0; rr < 16; ++rr) {
          float pv = __builtin_amdgcn_exp2f(st[f][rr] - mnew);
          st[f][rr] = pv;
          rsum += pv;
        }
#pragma unroll
        for (int g = 0; g < 4; ++g) {
          pd[f][2 * g]     = pk2(st[f][4 * g + 0], st[f][4 * g + 1]);
          pd[f][2 * g + 1] = pk2(st[f][4 * g + 2], st[f][4 * g + 3]);
        }
      }
    rsum += __shfl_xor(rsum, 32);
    lrow = lrow * alpha + rsum;

    // ---- O^T += V^T P^T; B-frags via lane-pair chunk swap ----
#pragma unroll
    for (int f = 0; f < 4; ++f)
      if (f < nf) {
#pragma unroll
        for (int hh = 0; hh < 2; ++hh) {
          u32 ss0 = lh ? pd[f][4 * hh + 0] : pd[f][4 * hh + 2];
          u32 ss1 = lh ? pd[f][4 * hh + 1] : pd[f][4 * hh + 3];
          u32 r0 = __shfl_xor(ss0, 32);
          u32 r1 = __shfl_xor(ss1, 32);
          uint4 b4;
          b4.x = lh ? r0 : pd[f][4 * hh + 0];
          b4.y = lh ? r1 : pd[f][4 * hh + 1];
          b4.z = lh ? pd[f][4 * hh + 2] : r0;
          b4.w = lh ? pd[f][4 * hh + 3] : r1;
          bf16x8 pb = __builtin_bit_cast(bf16x8, b4);
          const int ks = 2 * f + hh;
#pragma unroll
          for (int fd = 0; fd < 2; ++fd) {
            int d = fd * 32 + l31;
            bf16x8 vf = *(const bf16x8*)&Vs[d * 128 + (((2 * ks + lh) ^ (d & 15)) * 8)];
            accO[fd] = MFMA32(vf, pb, accO[fd]);
          }
        }
      }
  }

  // ---- epilogue: O^T[d][m] -> Y[s=s0+qm][h*64+d] ----
  float inv = 1.0f / lrow;
  u16* Yb = Yg + (n * 2048 + s0 + qm) * 512 + h * 64;
#pragma unroll
  for (int fd = 0; fd < 2; ++fd)
#pragma unroll
    for (int g = 0; g < 4; ++g) {
      ushort4 o;
      o.x = f2bf(accO[fd][4 * g + 0] * inv);
      o.y = f2bf(accO[fd][4 * g + 1] * inv);
      o.z = f2bf(accO[fd][4 * g + 2] * inv);
      o.w = f2bf(accO[fd][4 * g + 3] * inv);
      *(ushort4*)(Yb + fd * 32 + 8 * g + 4 * lh) = o;
    }
}

extern "C" void kernel_launch(void* const* d_in, const int* in_sizes, int n_in,
                              void* d_out, int out_size, void* d_ws, size_t ws_size,
                              hipStream_t stream) {
  (void)in_sizes; (void)n_in; (void)out_size; (void)ws_size;
  const float* query = (const float*)d_in[0];
  const float* key_  = (const float*)d_in[1];
  const float* value = (const float*)d_in[2];
  // d_in[3] = attn_mask (tril) — causal, applied structurally
  const float* Wq = (const float*)d_in[4];
  const float* bq = (const float*)d_in[5];
  const float* Wk = (const float*)d_in[6];
  const float* bk = (const float*)d_in[7];
  const float* Wv = (const float*)d_in[8];
  const float* bv = (const float*)d_in[9];
  const float* Wp = (const float*)d_in[10];
  const float* bp = (const float*)d_in[11];

  char* ws = (char*)d_ws;  // ~52 MB
  u16* qx  = (u16*)(ws);                // 8 MB; reused as y after q-proj consumed
  u16* kx  = (u16*)(ws + 8388608);      // 8 MB
  u16* vx  = (u16*)(ws + 16777216);     // 8 MB
  u16* wqx = (u16*)(ws + 25165824);     // 512 KB each
  u16* wkx = (u16*)(ws + 25690112);
  u16* wvx = (u16*)(ws + 26214400);
  u16* wpx = (u16*)(ws + 26738688);
  u16* qp  = (u16*)(ws + 27262976);     // 8 MB
  u16* kp  = (u16*)(ws + 35651584);     // 8 MB
  u16* vt  = (u16*)(ws + 44040192);     // 8 MB, V transposed [nh*64+d][2048]
  u16* y   = qx;

  cast_all<<<13312, 256, 0, stream>>>(query, key_, value, Wq, Wk, Wv, Wp,
                                      qx, kx, vx, wqx, wkx, wvx, wpx);
  gemm_qkv<<<1536, 128, 0, stream>>>(qx, kx, vx, wqx, wkx, wvx,
                                     bq, bk, bv, qp, kp, vt);
  attn_kernel<<<1024, 128, 0, stream>>>(qp, kp, vt, y);
  gemm_out<<<512, 128, 0, stream>>>(y, wpx, bp, (float*)d_out);
}